// Round 14
// baseline (512.790 us; speedup 1.0000x reference)
//
#include <hip/hip_runtime.h>
#include <math.h>

#define BB 8
#define LL 12
#define NN 1024
#define FF 3
#define HH 32
#define NDD 10
#define TTT 10
#define PP 3
#define DOUTT 128
constexpr float kALPHA = 3.0f;

typedef __attribute__((ext_vector_type(8))) short short8v;   // 8 bf16 (4 VGPR)
typedef __attribute__((ext_vector_type(4))) float float4v;

__device__ __forceinline__ unsigned short f2bf(float x) {
    union { float f; unsigned u; } v; v.f = x;
    unsigned r = v.u + 0x7FFF + ((v.u >> 16) & 1);
    return (unsigned short)(r >> 16);
}
__device__ __forceinline__ float bf2f(unsigned short u) {
    union { unsigned u; float f; } v; v.u = ((unsigned)u) << 16;
    return v.f;
}

// async global->LDS, 16B per lane. LDS dest = wave-uniform base + lane*16.
__device__ __forceinline__ void gload_lds16(const unsigned short* g, unsigned short* l) {
    __builtin_amdgcn_global_load_lds(
        (const __attribute__((address_space(1))) void*)g,
        (__attribute__((address_space(3))) void*)l,
        16, 0, 0);
}

// Stage a 128x32 bf16 tile into LDS (256 threads), XOR-swizzled:
// LDS chunk (row, ql) holds global chunk (row, ql ^ ((row>>1)&3)).
__device__ __forceinline__ void stage_tile(const unsigned short* __restrict__ g, int stride,
                                           unsigned short* tile, int tid) {
#pragma unroll
    for (int rr = 0; rr < 2; rr++) {
        int c = rr*256 + tid;
        int row = c >> 2;
        int q = (c & 3) ^ ((row >> 1) & 3);
        gload_lds16(g + (size_t)row*stride + q*8,
                    tile + ((size_t)(rr*256 + (tid & 192)))*8);
    }
}

// Stage a 128x32 tile with 512 threads (1 round).
__device__ __forceinline__ void stage_tileA512(const unsigned short* __restrict__ g, int stride,
                                               unsigned short* tile, int tid) {
    int row = tid >> 2;
    int q = (tid & 3) ^ ((row >> 1) & 3);
    gload_lds16(g + (size_t)row*stride + q*8,
                tile + ((size_t)(tid & ~63))*8);
}

// Stage a 256x32 tile with 512 threads (2 rounds).
__device__ __forceinline__ void stage_tile256_512(const unsigned short* __restrict__ g, int stride,
                                                  unsigned short* tile, int tid) {
#pragma unroll
    for (int rr = 0; rr < 2; rr++) {
        int c = rr*512 + tid;
        int row = c >> 2;
        int q = (c & 3) ^ ((row >> 1) & 3);
        gload_lds16(g + (size_t)row*stride + q*8,
                    tile + ((size_t)(rr*512 + (tid & ~63)))*8);
    }
}

// ---------------- workspace layout (floats) ----------------
constexpr size_t OFF_HIST    = 0;                                          // B*L*N*32
constexpr size_t OFF_S4      = OFF_HIST   + (size_t)BB*LL*NN*HH;           // B*L*N*4
constexpr size_t OFF_RATIO   = OFF_S4     + (size_t)BB*LL*NN*4;            // B*N*3
constexpr size_t OFF_CENT    = OFF_RATIO  + (size_t)BB*NN*3;               // 32
constexpr size_t OFF_M1      = OFF_CENT   + 32;                            // N*10
constexpr size_t OFF_M2      = OFF_M1     + (size_t)NN*NDD;                // N*10
constexpr size_t OFF_LABEL   = OFF_M2     + (size_t)NN*NDD;                // N ints
constexpr size_t OFF_AN      = OFF_LABEL  + NN;                            // N*N fp32
constexpr size_t OFF_ACOMBB  = OFF_AN     + (size_t)NN*NN;                 // N*N bf16
constexpr size_t OFF_FC1     = OFF_ACOMBB + (size_t)NN*NN/2;               // B*12*N*3 (partial, col-slice 1)
constexpr size_t OFF_HFINB   = OFF_FC1    + (size_t)NN*BB*HH*HH;           // N*8192 bf16 (slot reuse)
constexpr size_t OFF_WCOMBOT = OFF_HFINB  + (size_t)NN*BB*HH*HH/2;         // 128*32 bf16
constexpr size_t OFF_WE1B    = OFF_WCOMBOT+ 1024*4;                        // 128*32 bf16
constexpr size_t OFF_FC      = OFF_WE1B   + 1024*4;                        // B*12*N*3 (partial, col-slice 0)
constexpr size_t OFF_ANB     = OFF_FC     + (size_t)BB*LL*NN*3;            // 1024*1024 bf16
constexpr size_t OFF_ANBT    = OFF_ANB    + (size_t)NN*NN/2;               // 1024*1024 bf16
constexpr size_t OFF_X0T     = OFF_ANBT   + (size_t)NN*NN/2;               // 8192*1024 bf16
constexpr size_t OFF_W1HI    = OFF_X0T    + (size_t)BB*HH*HH*NN/2;         // 512*288 bf16
constexpr size_t OFF_FHB     = OFF_W1HI   + (size_t)512*288/2;             // 98304*288 bf16
constexpr size_t WS_FLOATS   = OFF_FHB    + (size_t)BB*LL*NN*288/2;        // ~150 MB

// ---------------- K1: embed + std decomposition + direct fhB[128..287] ----------------
__global__ __launch_bounds__(256) void k1_embed(
    const float* __restrict__ hd, const float* __restrict__ W_emb, const float* __restrict__ b_emb,
    const float* __restrict__ T_emb, const float* __restrict__ D_emb, const float* __restrict__ node_u,
    const float* __restrict__ W_std, const float* __restrict__ b_std,
    const float* __restrict__ W_mlp, const float* __restrict__ b_mlp,
    float* __restrict__ hist, unsigned short* __restrict__ fhB, float* __restrict__ s4)
{
    __shared__ float sW[2*62*32];
    for (int i = threadIdx.x; i < 2*62*32; i += 256) sW[i] = W_std[i];
    __syncthreads();

    int pos = blockIdx.x*256 + threadIdx.x;
    int n = pos & (NN-1);
    const float* hp = hd + (size_t)pos*5;
    float f0 = hp[0], f1 = hp[1], f2 = hp[2];
    int ti = (int)(hp[3]*288.0f);
    int di = (int)hp[4];

    float tv[10], dv[10], nu[10];
#pragma unroll
    for (int t = 0; t < 10; t++) {
        tv[t] = T_emb[ti*10+t]; dv[t] = D_emb[di*10+t]; nu[t] = node_u[n*10+t];
    }
    float h[32];
#pragma unroll
    for (int j = 0; j < 32; j++) h[j] = b_emb[j] + f0*W_emb[j] + f1*W_emb[32+j] + f2*W_emb[64+j];

    float a0[32], a1[32];
#pragma unroll
    for (int j = 0; j < 32; j++) { a0[j] = b_std[j]; a1[j] = b_std[32+j]; }

    auto accum = [&](float v, int i) {
#pragma unroll
        for (int q = 0; q < 8; q++) {
            float4 w0 = *(const float4*)&sW[i*32 + q*4];
            float4 w1 = *(const float4*)&sW[(62+i)*32 + q*4];
            a0[q*4+0] += v*w0.x; a0[q*4+1] += v*w0.y; a0[q*4+2] += v*w0.z; a0[q*4+3] += v*w0.w;
            a1[q*4+0] += v*w1.x; a1[q*4+1] += v*w1.y; a1[q*4+2] += v*w1.z; a1[q*4+3] += v*w1.w;
        }
    };
#pragma unroll
    for (int i = 0; i < 32; i++) accum(h[i], i);
#pragma unroll
    for (int i = 0; i < 10; i++) accum(nu[i], 32+i);
#pragma unroll
    for (int i = 0; i < 10; i++) accum(tv[i], 42+i);
#pragma unroll
    for (int i = 0; i < 10; i++) accum(dv[i], 52+i);

    float x0v[32], x1v[32], rv[32];
    float s0 = b_mlp[0], s1 = b_mlp[1], s2 = b_mlp[2], s3 = b_mlp[3];
#pragma unroll
    for (int j = 0; j < 32; j++) {
        float sg0 = 1.f/(1.f + __expf(-a0[j]));
        float sg1 = 1.f/(1.f + __expf(-a1[j]));
        x0v[j] = sg0*h[j]; x1v[j] = sg1*h[j]; rv[j] = h[j] - x0v[j] - x1v[j];
        s0 += h[j]  * W_mlp[j];
        s1 += x0v[j]* W_mlp[32+j];
        s2 += x1v[j]* W_mlp[64+j];
        s3 += rv[j] * W_mlp[96+j];
    }
    float* ho = hist + (size_t)pos*32;
#pragma unroll
    for (int q = 0; q < 8; q++)
        *(float4*)&ho[q*4] = make_float4(h[q*4], h[q*4+1], h[q*4+2], h[q*4+3]);

    unsigned short* fr = fhB + (size_t)pos*288;
#pragma unroll
    for (int q = 0; q < 4; q++) {
        short8v v;
#pragma unroll
        for (int e = 0; e < 8; e++) v[e] = (short)f2bf(fmaxf(h[q*8+e], 0.f));
        *(short8v*)&fr[128 + q*8] = v;
    }
#pragma unroll
    for (int q = 0; q < 4; q++) {
        short8v v;
#pragma unroll
        for (int e = 0; e < 8; e++) v[e] = (short)f2bf(fmaxf(x0v[q*8+e], 0.f));
        *(short8v*)&fr[160 + q*8] = v;
    }
#pragma unroll
    for (int q = 0; q < 4; q++) {
        short8v v;
#pragma unroll
        for (int e = 0; e < 8; e++) v[e] = (short)f2bf(fmaxf(x1v[q*8+e], 0.f));
        *(short8v*)&fr[192 + q*8] = v;
    }
#pragma unroll
    for (int q = 0; q < 4; q++) {
        short8v v;
#pragma unroll
        for (int e = 0; e < 8; e++) v[e] = (short)f2bf(fmaxf(rv[q*8+e], 0.f));
        *(short8v*)&fr[224 + q*8] = v;
    }
    float tail[32];
#pragma unroll
    for (int i = 0; i < 32; i++) tail[i] = (i < 10) ? tv[i] : ((i < 20) ? dv[i-10] : 0.f);
#pragma unroll
    for (int q = 0; q < 4; q++) {
        short8v v;
#pragma unroll
        for (int e = 0; e < 8; e++) v[e] = (short)f2bf(fmaxf(tail[q*8+e], 0.f));
        *(short8v*)&fr[256 + q*8] = v;
    }
    *(float4*)&s4[(size_t)pos*4] = make_float4(s0, s1, s2, s3);
}

// ---------------- K2: ratios ----------------
__global__ void k2_ratio(const float* __restrict__ s4, float* __restrict__ ratio)
{
    int bn = blockIdx.x*256 + threadIdx.x;
    if (bn >= BB*NN) return;
    int b = bn >> 10, n = bn & 1023;
    float a0=0, a1=0, a2=0, a3=0;
    for (int l = 0; l < 12; l++) {
        const float* sp = s4 + ((size_t)(b*12+l)*NN + n)*4;
        a0 += sp[0]; a1 += sp[1]; a2 += sp[2]; a3 += sp[3];
    }
    float hm = a0/12.f;
    float* rp = ratio + (size_t)bn*3;
    rp[0] = (a1/12.f)/(hm + 1e-6f);
    rp[1] = (a2/12.f)/(hm + 1e-6f);
    rp[2] = (a3/12.f)/(hm + 1e-6f);
}

// ---------------- K3: per-b centers ----------------
__global__ __launch_bounds__(256) void k3_centers(const float* __restrict__ ratio, float* __restrict__ centers)
{
    int b = blockIdx.x;
    float m0=-3.4e38f, m1v=-3.4e38f, m2v=-3.4e38f;
    for (int n = threadIdx.x; n < NN; n += 256) {
        const float* rp = ratio + ((size_t)b*NN + n)*3;
        m0 = fmaxf(m0, rp[0]); m1v = fmaxf(m1v, rp[1]); m2v = fmaxf(m2v, rp[2]);
    }
#pragma unroll
    for (int off = 32; off > 0; off >>= 1) {
        m0  = fmaxf(m0,  __shfl_down(m0,  off));
        m1v = fmaxf(m1v, __shfl_down(m1v, off));
        m2v = fmaxf(m2v, __shfl_down(m2v, off));
    }
    __shared__ float red[4][3];
    int wid = threadIdx.x >> 6, lane = threadIdx.x & 63;
    if (lane == 0) { red[wid][0]=m0; red[wid][1]=m1v; red[wid][2]=m2v; }
    __syncthreads();
    if (threadIdx.x == 0) {
        centers[b*3+0] = fmaxf(fmaxf(red[0][0],red[1][0]), fmaxf(red[2][0],red[3][0]));
        centers[b*3+1] = fmaxf(fmaxf(red[0][1],red[1][1]), fmaxf(red[2][1],red[3][1]));
        centers[b*3+2] = fmaxf(fmaxf(red[0][2],red[1][2]), fmaxf(red[2][2],red[3][2]));
    }
}

// ---------------- K4: labels + m1/m2 ----------------
__global__ void k4_labels(const float* __restrict__ ratio, const float* __restrict__ centers,
                          const float* __restrict__ node_u, const float* __restrict__ node_d,
                          int* __restrict__ label, float* __restrict__ m1, float* __restrict__ m2)
{
    int n = blockIdx.x*256 + threadIdx.x;
    if (n >= NN) return;
    int c0=0, c1=0, c2=0;
    for (int b = 0; b < BB; b++) {
        const float* rp = ratio + ((size_t)b*NN + n)*3;
        const float* cp = centers + b*3;
        float d0 = fabsf(rp[0]-cp[0]), d1 = fabsf(rp[1]-cp[1]), d2 = fabsf(rp[2]-cp[2]);
        int a = 0; float best = d0;
        if (d1 < best) { best = d1; a = 1; }
        if (d2 < best) { best = d2; a = 2; }
        if (a == 0) c0++; else if (a == 1) c1++; else c2++;
    }
    int lab = 0, bc = c0;
    if (c1 > bc) { bc = c1; lab = 1; }
    if (c2 > bc) { bc = c2; lab = 2; }
    label[n] = lab;
#pragma unroll
    for (int d = 0; d < 10; d++) {
        m1[n*10+d] = tanhf(kALPHA*node_u[n*10+d]);
        m2[n*10+d] = tanhf(kALPHA*node_d[n*10+d]);
    }
}

// ---------------- K5: An ----------------
__global__ __launch_bounds__(256) void k5_A(const float* __restrict__ m1, const float* __restrict__ m2,
                                            const int* __restrict__ label, float* __restrict__ An)
{
    int n = blockIdx.x;
    __shared__ float row[1024];
    __shared__ float m1n[10], m2n[10];
    __shared__ float ssum[4];
    int t = threadIdx.x;
    if (t < 10) { m1n[t] = m1[n*10+t]; m2n[t] = m2[n*10+t]; }
    __syncthreads();
    int labn = label[n];
    float lsum = 0.f;
    for (int m = t; m < 1024; m += 256) {
        float a = 0.f;
        if (label[m] == labn) {
            float x = 0.f;
#pragma unroll
            for (int d = 0; d < 10; d++) x += m1n[d]*m2[m*10+d] - m2n[d]*m1[m*10+d];
            a = fmaxf(tanhf(3.f*x), 0.f);
        }
        row[m] = a; lsum += a;
    }
#pragma unroll
    for (int off = 32; off > 0; off >>= 1) lsum += __shfl_down(lsum, off);
    int wid = t >> 6, lane = t & 63;
    if (lane == 0) ssum[wid] = lsum;
    __syncthreads();
    float inv = 1.f/((ssum[0]+ssum[1]+ssum[2]+ssum[3]) + 1e-6f);
    for (int m = t; m < 1024; m += 256) An[(size_t)n*1024 + m] = row[m]*inv;
}

// ---------------- transpose fp32 [R][C] -> bf16 outT[C][R] ----------------
template<bool ALSO_DIRECT>
__global__ __launch_bounds__(256) void kt_transpose(const float* __restrict__ in,
                                                    unsigned short* __restrict__ outT,
                                                    unsigned short* __restrict__ outD,
                                                    int R, int C)
{
    __shared__ float tile[64][65];
    int c0 = blockIdx.x*64, r0 = blockIdx.y*64;
    for (int i = threadIdx.x; i < 64*64; i += 256) {
        int r = i >> 6, c = i & 63;
        float v = in[(size_t)(r0+r)*C + c0+c];
        tile[r][c] = v;
        if (ALSO_DIRECT) outD[(size_t)(r0+r)*C + c0+c] = f2bf(v);
    }
    __syncthreads();
    for (int i = threadIdx.x; i < 64*64; i += 256) {
        int c = i >> 6, r = i & 63;
        outT[(size_t)(c0+c)*R + r0+r] = f2bf(tile[r][c]);
    }
}

// ---------------- bf16 MFMA GEMM, 128x128 tile, BK=64, 2-phase dbuf ----------------
// MODE 0: AcombB(bf16) = bf16(0.9025*acc + 0.0475*A + 0.05*I)
// MODE 2: C(bf16) = acc
template<int MODE>
__global__ __launch_bounds__(256) void gemm_mfma(
    const unsigned short* __restrict__ A, const unsigned short* __restrict__ B,
    void* __restrict__ Cout, int Nout, int K)
{
    __shared__ __align__(16) unsigned short lds[2][2][2][128*32];   // 64 KB
    const int t = threadIdx.x;

    int id = blockIdx.x + gridDim.x*blockIdx.y;
    int gx8 = gridDim.x >> 3;
    int xcd = id & 7, local = id >> 3;
    int bx = xcd*gx8 + (local % gx8);
    int by = local / gx8;

    const int lane = t & 63, wid = t >> 6;
    const int wr = wid >> 1, wc = wid & 1;
    const int l15 = lane & 15, l4 = lane >> 4;
    const int swq8 = (l4 ^ ((l15 >> 1) & 3))*8;
    const int row0 = by*128, col0 = bx*128;

    float4v acc[4][4];
#pragma unroll
    for (int i = 0; i < 4; i++)
#pragma unroll
        for (int j = 0; j < 4; j++) acc[i][j] = (float4v){0.f,0.f,0.f,0.f};

    const unsigned short* Ab = A + (size_t)row0*K;
    const unsigned short* Bb = B + (size_t)col0*K;

    stage_tile(Ab +  0, K, lds[0][0][0], t); stage_tile(Bb +  0, K, lds[0][1][0], t);
    stage_tile(Ab + 32, K, lds[0][0][1], t); stage_tile(Bb + 32, K, lds[0][1][1], t);
    __syncthreads();

    const int nk = K >> 6;
    for (int ks = 0; ks < nk; ks++) {
        int cur = ks & 1;
        if (ks + 1 < nk) {
            stage_tile(Ab + (ks+1)*64,      K, lds[cur^1][0][0], t);
            stage_tile(Bb + (ks+1)*64,      K, lds[cur^1][1][0], t);
            stage_tile(Ab + (ks+1)*64 + 32, K, lds[cur^1][0][1], t);
            stage_tile(Bb + (ks+1)*64 + 32, K, lds[cur^1][1][1], t);
        }
#pragma unroll
        for (int kk = 0; kk < 2; kk++) {
            short8v a[4], b[4];
#pragma unroll
            for (int f = 0; f < 4; f++) {
                a[f] = *(const short8v*)&lds[cur][0][kk][(wr*64 + f*16 + l15)*32 + swq8];
                b[f] = *(const short8v*)&lds[cur][1][kk][(wc*64 + f*16 + l15)*32 + swq8];
            }
#pragma unroll
            for (int i = 0; i < 4; i++)
#pragma unroll
                for (int j = 0; j < 4; j++)
                    acc[i][j] = __builtin_amdgcn_mfma_f32_16x16x32_bf16(a[i], b[j], acc[i][j], 0, 0, 0);
        }
        __syncthreads();
    }

#pragma unroll
    for (int i = 0; i < 4; i++) {
#pragma unroll
        for (int j = 0; j < 4; j++) {
            int gc = col0 + wc*64 + j*16 + l15;
#pragma unroll
            for (int r = 0; r < 4; r++) {
                int gr = row0 + wr*64 + i*16 + l4*4 + r;
                if (MODE == 0) {
                    float an = bf2f(A[(size_t)gr*K + gc]);
                    float v = 0.9025f*acc[i][j][r] + 0.0475f*an + ((gr==gc) ? 0.05f : 0.f);
                    ((unsigned short*)Cout)[(size_t)gr*Nout + gc] = f2bf(v);
                } else {
                    ((unsigned short*)Cout)[(size_t)gr*Nout + gc] = f2bf(acc[i][j][r]);
                }
            }
        }
    }
}

// ---------------- K7T: fused x0 compute + transpose -> x0T bf16 [8192 col][1024 n] ----------------
__global__ __launch_bounds__(256) void k7t_x0T(
    const float* __restrict__ hist, const float* __restrict__ W_start, const float* __restrict__ b_start,
    unsigned short* __restrict__ x0T)
{
    __shared__ float hl[12*1056];   // [l][nn*33 + h]
    __shared__ float sw[384];       // [c*12+l]
    __shared__ float sb[32];

    const int b = blockIdx.x >> 5;
    const int n0 = (blockIdx.x & 31)*32;
    const int t = threadIdx.x;

    for (int i = t; i < 384; i += 256) sw[i] = W_start[i];
    if (t < 32) sb[t] = b_start[t];
#pragma unroll
    for (int l = 0; l < 12; l++) {
        float4 v = ((const float4*)(hist + ((size_t)(b*12+l)*NN + n0)*32))[t];
        int nn = t >> 3, h4 = (t & 7)*4;
        float* d = &hl[l*1056 + nn*33 + h4];
        d[0] = v.x; d[1] = v.y; d[2] = v.z; d[3] = v.w;
    }
    __syncthreads();

    const int n = t & 31;
    const int c0base = t >> 5;
    for (int it = 0; it < 128; it++) {
        int col = c0base + it*8;
        int c = col >> 5, h = col & 31;
        float s = sb[c];
#pragma unroll
        for (int l = 0; l < 12; l++) s += sw[c*12+l]*hl[l*1056 + n*33 + h];
        x0T[((size_t)(b*1024 + col))*1024 + n0 + n] = f2bf(s);
    }
}

// ---------------- Kw: wcomboT bf16 [128 j][32 h] + we1B bf16 [128 o1][32 c] ----------------
__global__ void kw_combo2(const float* __restrict__ W_g, const float* __restrict__ W_rnn,
                          const float* __restrict__ W_e1,
                          unsigned short* __restrict__ wcomboT, unsigned short* __restrict__ we1B)
{
    int j = threadIdx.x;  // 128
    for (int hh = 0; hh < 32; hh++) {
        float s = 0.f;
        for (int k = 0; k < 32; k++) s += (W_g[hh*32+k] + W_g[1024 + hh*32+k]) * W_rnn[k*128 + j];
        wcomboT[j*32 + hh] = f2bf(s);
    }
    for (int i = j; i < 4096; i += 128) we1B[i] = f2bf(W_e1[i]);
}

// ---------------- K9 MFMA ----------------
__global__ __launch_bounds__(256) void k9_mfma(
    const unsigned short* __restrict__ hfinB,    // [N][8192] bf16
    const unsigned short* __restrict__ wcomboT,  // [128][32] bf16
    const float* __restrict__ b_rnn,
    const unsigned short* __restrict__ we1B,     // [128][32] bf16
    const float* __restrict__ b_e1,
    const float* __restrict__ W_e2,              // [12][128]
    const float* __restrict__ b_e2,
    const float* __restrict__ Mm,                // [N][128]
    unsigned short* __restrict__ fhB)            // [98304][288], cols 0..127
{
    __shared__ __align__(16) unsigned short xrT[4][1024];
    __shared__ float sWe2T[128][12];
    __shared__ float sBe1[128];
    __shared__ float sBe2[16];

    const int t = threadIdx.x;
    const int bid = blockIdx.x;
    const int n = bid & (NN-1), b = bid >> 10;
    const int lane = t & 63, wid = t >> 6;
    const int l15 = lane & 15, l4 = lane >> 4;
    const int j0 = wid*32;

    for (int i = t; i < 12*128; i += 256) {
        int o2 = i >> 7, o1 = i & 127;
        sWe2T[o1][o2] = W_e2[i];
    }
    if (t < 128) sBe1[t] = b_e1[t];
    if (t < 12)  sBe2[t] = b_e2[t];
    __syncthreads();

    const unsigned short* Hb = hfinB + (size_t)n*8192 + (size_t)b*1024;
    short8v ah[2], bw[2];
#pragma unroll
    for (int f = 0; f < 2; f++) {
        ah[f] = *(const short8v*)&Hb[(f*16 + l15)*32 + l4*8];
        bw[f] = *(const short8v*)&wcomboT[(j0 + f*16 + l15)*32 + l4*8];
    }
    float br[2];
    br[0] = b_rnn[j0 + l15];
    br[1] = b_rnn[j0 + 16 + l15];
    float4v accA[2][2];
#pragma unroll
    for (int cf = 0; cf < 2; cf++)
#pragma unroll
        for (int jf = 0; jf < 2; jf++)
            accA[cf][jf] = (float4v){br[jf], br[jf], br[jf], br[jf]};
#pragma unroll
    for (int cf = 0; cf < 2; cf++)
#pragma unroll
        for (int jf = 0; jf < 2; jf++)
            accA[cf][jf] = __builtin_amdgcn_mfma_f32_16x16x32_bf16(ah[cf], bw[jf], accA[cf][jf], 0, 0, 0);

#pragma unroll
    for (int cf = 0; cf < 2; cf++)
#pragma unroll
        for (int jf = 0; jf < 2; jf++) {
            int jl = jf*16 + l15;
            int csw = (cf*16 + l4*4) ^ ((jl & 3) << 3);
            unsigned short p0 = f2bf(tanhf(accA[cf][jf][0]));
            unsigned short p1 = f2bf(tanhf(accA[cf][jf][1]));
            unsigned short p2 = f2bf(tanhf(accA[cf][jf][2]));
            unsigned short p3 = f2bf(tanhf(accA[cf][jf][3]));
            unsigned int lo = (unsigned)p0 | ((unsigned)p1 << 16);
            unsigned int hi = (unsigned)p2 | ((unsigned)p3 << 16);
            *(uint2*)&xrT[wid][jl*32 + csw] = make_uint2(lo, hi);
        }

    short8v bx[2];
#pragma unroll
    for (int jf = 0; jf < 2; jf++) {
        int jl = jf*16 + l15;
        int csw = (l4*8) ^ ((jl & 3) << 3);
        bx[jf] = *(const short8v*)&xrT[wid][jl*32 + csw];
    }
    float4v accB[8][2];
#pragma unroll
    for (int of = 0; of < 8; of++)
#pragma unroll
        for (int jf = 0; jf < 2; jf++) accB[of][jf] = (float4v){0.f,0.f,0.f,0.f};
#pragma unroll
    for (int of = 0; of < 8; of++) {
        short8v aw = *(const short8v*)&we1B[(of*16 + l15)*32 + l4*8];
        accB[of][0] = __builtin_amdgcn_mfma_f32_16x16x32_bf16(aw, bx[0], accB[of][0], 0, 0, 0);
        accB[of][1] = __builtin_amdgcn_mfma_f32_16x16x32_bf16(aw, bx[1], accB[of][1], 0, 0, 0);
    }

    float v0[12], v1[12];
#pragma unroll
    for (int o2 = 0; o2 < 12; o2++) { v0[o2] = 0.f; v1[o2] = 0.f; }
#pragma unroll
    for (int of = 0; of < 8; of++) {
#pragma unroll
        for (int r = 0; r < 4; r++) {
            int o1 = of*16 + l4*4 + r;
            float be = sBe1[o1];
            float z0 = fmaxf(accB[of][0][r] + be, 0.f);
            float z1 = fmaxf(accB[of][1][r] + be, 0.f);
#pragma unroll
            for (int q = 0; q < 3; q++) {
                float4 w = *(const float4*)&sWe2T[o1][q*4];
                v0[q*4+0] += w.x*z0; v0[q*4+1] += w.y*z0; v0[q*4+2] += w.z*z0; v0[q*4+3] += w.w*z0;
                v1[q*4+0] += w.x*z1; v1[q*4+1] += w.y*z1; v1[q*4+2] += w.z*z1; v1[q*4+3] += w.w*z1;
            }
        }
    }
#pragma unroll
    for (int o2 = 0; o2 < 12; o2++) {
        v0[o2] += __shfl_xor(v0[o2], 16);
        v0[o2] += __shfl_xor(v0[o2], 32);
        v1[o2] += __shfl_xor(v1[o2], 16);
        v1[o2] += __shfl_xor(v1[o2], 32);
    }

    float mm0 = Mm[(size_t)n*128 + j0 + l15];
    float mm1 = Mm[(size_t)n*128 + j0 + 16 + l15];
#pragma unroll
    for (int e = 0; e < 3; e++) {
        int o2 = l4*3 + e;
        float be2 = sBe2[o2];
        size_t base = ((size_t)((b*12 + o2)*NN + n))*288;
        float val0 = (v0[o2] + be2) * mm0;
        float val1 = (v1[o2] + be2) * mm1;
        fhB[base + j0 + l15]      = f2bf(fmaxf(val0, 0.f));
        fhB[base + j0 + 16 + l15] = f2bf(fmaxf(val1, 0.f));
    }
}

// ---------------- kt_w1: W_f1 -> bf16 [512][288] (n-major) ----------------
__global__ void kt_w1(const float* __restrict__ W_f1, unsigned short* __restrict__ w1hi)
{
    int idx = blockIdx.x*256 + threadIdx.x;
    if (idx >= 512*288) return;
    int n = idx / 288, k = idx - n*288;
    float w = (k < 276) ? W_f1[(size_t)k*512 + n] : 0.f;
    w1hi[idx] = f2bf(w);
}

// ---------------- K10 v7: 128x256 tile, 48 KB LDS -> 3 blocks/CU, direct partial-fc store ----------------
// 1536 blocks (8*192, XCD-bijective; (by,0),(by,1) co-XCD). 8 waves: 2 row x 4 col groups.
__global__ __launch_bounds__(512, 2) void k10_mfma3(
    const unsigned short* __restrict__ fhB, const unsigned short* __restrict__ w1hi,
    const float* __restrict__ b_f1, const float* __restrict__ W_f2,
    float* __restrict__ fc0, float* __restrict__ fc1)
{
    __shared__ __align__(16) unsigned short smem[24576];   // 48 KB
    unsigned short (*Abuf)[128*32] = (unsigned short(*)[128*32])smem;             // 16 KB
    unsigned short (*Bbuf)[256*32] = (unsigned short(*)[256*32])(smem + 8192);    // 32 KB
    float* fcp = (float*)smem;                                                     // epilogue alias

    const int t = threadIdx.x;
    int id = blockIdx.x;                          // 1536 = 8*192
    int sid = (id & 7)*192 + (id >> 3);
    const int by = sid >> 1, bx = sid & 1;
    const int pos0 = by*128, col0 = bx*256;

    const int lane = t & 63, w = t >> 6;
    const int wr = w >> 2, wc = w & 3;            // 2 row-groups x 4 col-groups (64x64 each)
    const int l15 = lane & 15, l4 = lane >> 4;
    const int swq8 = (l4 ^ ((l15 >> 1) & 3))*8;

    float4v acc[4][4];
#pragma unroll
    for (int i = 0; i < 4; i++)
#pragma unroll
        for (int j = 0; j < 4; j++) acc[i][j] = (float4v){0.f,0.f,0.f,0.f};

    const unsigned short* Ab = fhB  + (size_t)pos0*288;
    const unsigned short* Bb = w1hi + (size_t)col0*288;

    stage_tileA512(Ab, 288, Abuf[0], t);
    stage_tile256_512(Bb, 288, Bbuf[0], t);
    __syncthreads();

    for (int ks = 0; ks < 9; ks++) {
        int cur = ks & 1;
        if (ks + 1 < 9) {
            stage_tileA512(Ab + (ks+1)*32, 288, Abuf[cur^1], t);
            stage_tile256_512(Bb + (ks+1)*32, 288, Bbuf[cur^1], t);
        }
        short8v a[4], b[4];
#pragma unroll
        for (int f = 0; f < 4; f++) {
            a[f] = *(const short8v*)&Abuf[cur][(wr*64 + f*16 + l15)*32 + swq8];
            b[f] = *(const short8v*)&Bbuf[cur][(wc*64 + f*16 + l15)*32 + swq8];
        }
#pragma unroll
        for (int i = 0; i < 4; i++)
#pragma unroll
            for (int j = 0; j < 4; j++)
                acc[i][j] = __builtin_amdgcn_mfma_f32_16x16x32_bf16(a[i], b[j], acc[i][j], 0, 0, 0);
        __syncthreads();
    }

    // epilogue: fcp (aliases Abuf) zero, z = relu(acc+b_f1), contract with W_f2 slice
    for (int i = t; i < 384; i += 512) fcp[i] = 0.f;
    __syncthreads();

    float pk[4][4][3];
#pragma unroll
    for (int i = 0; i < 4; i++)
#pragma unroll
        for (int r = 0; r < 4; r++)
#pragma unroll
            for (int k = 0; k < 3; k++) pk[i][r][k] = 0.f;

#pragma unroll
    for (int j = 0; j < 4; j++) {
        int gc = col0 + wc*64 + j*16 + l15;
        float bias = b_f1[gc];
        float w20 = W_f2[gc*3+0], w21 = W_f2[gc*3+1], w22 = W_f2[gc*3+2];
#pragma unroll
        for (int i = 0; i < 4; i++)
#pragma unroll
            for (int r = 0; r < 4; r++) {
                float z = fmaxf(acc[i][j][r] + bias, 0.f);
                pk[i][r][0] += z*w20; pk[i][r][1] += z*w21; pk[i][r][2] += z*w22;
            }
    }
#pragma unroll
    for (int i = 0; i < 4; i++)
#pragma unroll
        for (int r = 0; r < 4; r++) {
            int rowL = wr*64 + i*16 + l4*4 + r;
            atomicAdd(&fcp[rowL*3 + 0], pk[i][r][0]);
            atomicAdd(&fcp[rowL*3 + 1], pk[i][r][1]);
            atomicAdd(&fcp[rowL*3 + 2], pk[i][r][2]);
        }
    __syncthreads();
    float* fcout = bx ? fc1 : fc0;
    for (int i = t; i < 384; i += 512) {
        fcout[(size_t)pos0*3 + i] = fcp[i];
    }
}

// ---------------- K11: e3 epilogue + transpose (sums the two fc partials) ----------------
__global__ void k11_e3(const float* __restrict__ fc0, const float* __restrict__ fc1,
                       const float* __restrict__ b_f2,
                       const float* __restrict__ W_e3, const float* __restrict__ b_e3,
                       float* __restrict__ out)
{
    int idx = blockIdx.x*256 + threadIdx.x;
    if (idx >= BB*NN*12) return;
    int ok = idx % 12;
    int o = ok / 3, k = ok % 3;
    int bn = idx / 12;
    int n = bn & 1023, b = bn >> 10;
    float s = b_e3[o];
    float bk = b_f2[k];
#pragma unroll
    for (int c = 0; c < 12; c++) {
        size_t p = ((size_t)(b*12+c)*NN + n)*3 + k;
        s += W_e3[o*12+c] * (fc0[p] + fc1[p] + bk);
    }
    out[idx] = s;
}

extern "C" void kernel_launch(void* const* d_in, const int* in_sizes, int n_in,
                              void* d_out, int out_size, void* d_ws, size_t ws_size,
                              hipStream_t stream)
{
    const float* hd      = (const float*)d_in[0];
    const float* W_emb   = (const float*)d_in[1];
    const float* b_emb   = (const float*)d_in[2];
    const float* T_emb   = (const float*)d_in[3];
    const float* D_emb   = (const float*)d_in[4];
    const float* node_u  = (const float*)d_in[5];
    const float* node_d  = (const float*)d_in[6];
    const float* W_std   = (const float*)d_in[7];
    const float* b_std   = (const float*)d_in[8];
    const float* W_mlp   = (const float*)d_in[9];
    const float* b_mlp   = (const float*)d_in[10];
    const float* W_start = (const float*)d_in[11];
    const float* b_start = (const float*)d_in[12];
    const float* W_g     = (const float*)d_in[13];
    const float* W_rnn   = (const float*)d_in[14];
    const float* b_rnn   = (const float*)d_in[15];
    const float* W_e1    = (const float*)d_in[16];
    const float* b_e1    = (const float*)d_in[17];
    const float* W_e2    = (const float*)d_in[18];
    const float* b_e2    = (const float*)d_in[19];
    const float* Mm      = (const float*)d_in[20];
    const float* W_f1    = (const float*)d_in[21];
    const float* b_f1    = (const float*)d_in[22];
    const float* W_f2    = (const float*)d_in[23];
    const float* b_f2    = (const float*)d_in[24];
    const float* W_e3    = (const float*)d_in[25];
    const float* b_e3    = (const float*)d_in[26];

    float* ws      = (float*)d_ws;
    float* hist    = ws + OFF_HIST;
    float* s4      = ws + OFF_S4;
    float* ratio   = ws + OFF_RATIO;
    float* cent    = ws + OFF_CENT;
    float* m1      = ws + OFF_M1;
    float* m2      = ws + OFF_M2;
    int*   label   = (int*)(ws + OFF_LABEL);
    float* An      = ws + OFF_AN;
    unsigned short* AcombB  = (unsigned short*)(ws + OFF_ACOMBB);
    unsigned short* hfinB   = (unsigned short*)(ws + OFF_HFINB);
    unsigned short* wcomboT = (unsigned short*)(ws + OFF_WCOMBOT);
    unsigned short* we1B    = (unsigned short*)(ws + OFF_WE1B);
    float* fc0     = ws + OFF_FC;
    float* fc1     = ws + OFF_FC1;
    unsigned short* AnB   = (unsigned short*)(ws + OFF_ANB);
    unsigned short* AnBT  = (unsigned short*)(ws + OFF_ANBT);
    unsigned short* x0T   = (unsigned short*)(ws + OFF_X0T);
    unsigned short* w1hi  = (unsigned short*)(ws + OFF_W1HI);
    unsigned short* fhB   = (unsigned short*)(ws + OFF_FHB);

    k1_embed<<<(BB*LL*NN)/256, 256, 0, stream>>>(hd, W_emb, b_emb, T_emb, D_emb, node_u,
                                                 W_std, b_std, W_mlp, b_mlp, hist, fhB, s4);
    k2_ratio<<<(BB*NN)/256, 256, 0, stream>>>(s4, ratio);
    k3_centers<<<BB, 256, 0, stream>>>(ratio, cent);
    k4_labels<<<NN/256, 256, 0, stream>>>(ratio, cent, node_u, node_d, label, m1, m2);
    k5_A<<<NN, 256, 0, stream>>>(m1, m2, label, An);
    kt_transpose<true><<<dim3(16, 16), 256, 0, stream>>>(An, AnBT, AnB, 1024, 1024);
    gemm_mfma<0><<<dim3(8, 8), 256, 0, stream>>>(AnB, AnBT, AcombB, 1024, 1024);
    k7t_x0T<<<256, 256, 0, stream>>>(hist, W_start, b_start, x0T);
    gemm_mfma<2><<<dim3(64, 8), 256, 0, stream>>>(AcombB, x0T, hfinB, 8192, 1024);
    kw_combo2<<<1, 128, 0, stream>>>(W_g, W_rnn, W_e1, wcomboT, we1B);
    k9_mfma<<<BB*NN, 256, 0, stream>>>(hfinB, wcomboT, b_rnn, we1B, b_e1, W_e2, b_e2, Mm, fhB);
    kt_w1<<<(512*288)/256, 256, 0, stream>>>(W_f1, w1hi);
    k10_mfma3<<<1536, 512, 0, stream>>>(fhB, w1hi, b_f1, W_f2, fc0, fc1);
    k11_e3<<<(BB*NN*12)/256, 256, 0, stream>>>(fc0, fc1, b_f2, W_e3, b_e3, (float*)d_out);
}

// Round 15
// 397.784 us; speedup vs baseline: 1.2891x; 1.2891x over previous
//
#include <hip/hip_runtime.h>
#include <math.h>

#define BB 8
#define LL 12
#define NN 1024
#define FF 3
#define HH 32
#define NDD 10
#define TTT 10
#define PP 3
#define DOUTT 128
constexpr float kALPHA = 3.0f;

typedef __attribute__((ext_vector_type(8))) short short8v;   // 8 bf16 (4 VGPR)
typedef __attribute__((ext_vector_type(4))) float float4v;

__device__ __forceinline__ unsigned short f2bf(float x) {
    union { float f; unsigned u; } v; v.f = x;
    unsigned r = v.u + 0x7FFF + ((v.u >> 16) & 1);
    return (unsigned short)(r >> 16);
}
__device__ __forceinline__ float bf2f(unsigned short u) {
    union { unsigned u; float f; } v; v.u = ((unsigned)u) << 16;
    return v.f;
}

// async global->LDS, 16B per lane. LDS dest = wave-uniform base + lane*16.
__device__ __forceinline__ void gload_lds16(const unsigned short* g, unsigned short* l) {
    __builtin_amdgcn_global_load_lds(
        (const __attribute__((address_space(1))) void*)g,
        (__attribute__((address_space(3))) void*)l,
        16, 0, 0);
}

// Stage a 128x32 bf16 tile into LDS (256 threads), XOR-swizzled:
// LDS chunk (row, ql) holds global chunk (row, ql ^ ((row>>1)&3)).
__device__ __forceinline__ void stage_tile(const unsigned short* __restrict__ g, int stride,
                                           unsigned short* tile, int tid) {
#pragma unroll
    for (int rr = 0; rr < 2; rr++) {
        int c = rr*256 + tid;
        int row = c >> 2;
        int q = (c & 3) ^ ((row >> 1) & 3);
        gload_lds16(g + (size_t)row*stride + q*8,
                    tile + ((size_t)(rr*256 + (tid & 192)))*8);
    }
}

// Stage a 128x32 tile with 512 threads (1 round).
__device__ __forceinline__ void stage_tileA512(const unsigned short* __restrict__ g, int stride,
                                               unsigned short* tile, int tid) {
    int row = tid >> 2;
    int q = (tid & 3) ^ ((row >> 1) & 3);
    gload_lds16(g + (size_t)row*stride + q*8,
                tile + ((size_t)(tid & ~63))*8);
}

// Stage a 512x32 tile with 512 threads (4 rounds).
__device__ __forceinline__ void stage_tileB512(const unsigned short* __restrict__ g, int stride,
                                               unsigned short* tile, int tid) {
#pragma unroll
    for (int rr = 0; rr < 4; rr++) {
        int c = rr*512 + tid;
        int row = c >> 2;
        int q = (c & 3) ^ ((row >> 1) & 3);
        gload_lds16(g + (size_t)row*stride + q*8,
                    tile + ((size_t)(rr*512 + (tid & ~63)))*8);
    }
}

// ---------------- workspace layout (floats) ----------------
constexpr size_t OFF_HIST    = 0;                                          // B*L*N*32
constexpr size_t OFF_S4      = OFF_HIST   + (size_t)BB*LL*NN*HH;           // B*L*N*4
constexpr size_t OFF_RATIO   = OFF_S4     + (size_t)BB*LL*NN*4;            // B*N*3
constexpr size_t OFF_CENT    = OFF_RATIO  + (size_t)BB*NN*3;               // 32
constexpr size_t OFF_M1      = OFF_CENT   + 32;                            // N*10
constexpr size_t OFF_M2      = OFF_M1     + (size_t)NN*NDD;                // N*10
constexpr size_t OFF_LABEL   = OFF_M2     + (size_t)NN*NDD;                // N ints
constexpr size_t OFF_AN      = OFF_LABEL  + NN;                            // N*N fp32
constexpr size_t OFF_ACOMBB  = OFF_AN     + (size_t)NN*NN;                 // N*N bf16
constexpr size_t OFF_X0      = OFF_ACOMBB + (size_t)NN*NN/2;               // (unused slot)
constexpr size_t OFF_HFINB   = OFF_X0     + (size_t)NN*BB*HH*HH;           // N*8192 bf16
constexpr size_t OFF_WCOMBOT = OFF_HFINB  + (size_t)NN*BB*HH*HH/2;         // 128*32 bf16
constexpr size_t OFF_WE1B    = OFF_WCOMBOT+ 1024*4;                        // 128*32 bf16
constexpr size_t OFF_FC      = OFF_WE1B   + 1024*4;                        // B*12*N*3
constexpr size_t OFF_ANB     = OFF_FC     + (size_t)BB*LL*NN*3;            // 1024*1024 bf16
constexpr size_t OFF_ANBT    = OFF_ANB    + (size_t)NN*NN/2;               // 1024*1024 bf16
constexpr size_t OFF_X0T     = OFF_ANBT   + (size_t)NN*NN/2;               // 8192*1024 bf16
constexpr size_t OFF_W1HI    = OFF_X0T    + (size_t)BB*HH*HH*NN/2;         // 512*288 bf16
constexpr size_t OFF_FHB     = OFF_W1HI   + (size_t)512*288/2;             // 98304*288 bf16
constexpr size_t WS_FLOATS   = OFF_FHB    + (size_t)BB*LL*NN*288/2;        // ~150 MB

// ---------------- K1: embed + std decomposition + direct fhB[128..287] ----------------
__global__ __launch_bounds__(256) void k1_embed(
    const float* __restrict__ hd, const float* __restrict__ W_emb, const float* __restrict__ b_emb,
    const float* __restrict__ T_emb, const float* __restrict__ D_emb, const float* __restrict__ node_u,
    const float* __restrict__ W_std, const float* __restrict__ b_std,
    const float* __restrict__ W_mlp, const float* __restrict__ b_mlp,
    float* __restrict__ hist, unsigned short* __restrict__ fhB, float* __restrict__ s4)
{
    __shared__ float sW[2*62*32];
    for (int i = threadIdx.x; i < 2*62*32; i += 256) sW[i] = W_std[i];
    __syncthreads();

    int pos = blockIdx.x*256 + threadIdx.x;
    int n = pos & (NN-1);
    const float* hp = hd + (size_t)pos*5;
    float f0 = hp[0], f1 = hp[1], f2 = hp[2];
    int ti = (int)(hp[3]*288.0f);
    int di = (int)hp[4];

    float tv[10], dv[10], nu[10];
#pragma unroll
    for (int t = 0; t < 10; t++) {
        tv[t] = T_emb[ti*10+t]; dv[t] = D_emb[di*10+t]; nu[t] = node_u[n*10+t];
    }
    float h[32];
#pragma unroll
    for (int j = 0; j < 32; j++) h[j] = b_emb[j] + f0*W_emb[j] + f1*W_emb[32+j] + f2*W_emb[64+j];

    float a0[32], a1[32];
#pragma unroll
    for (int j = 0; j < 32; j++) { a0[j] = b_std[j]; a1[j] = b_std[32+j]; }

    auto accum = [&](float v, int i) {
#pragma unroll
        for (int q = 0; q < 8; q++) {
            float4 w0 = *(const float4*)&sW[i*32 + q*4];
            float4 w1 = *(const float4*)&sW[(62+i)*32 + q*4];
            a0[q*4+0] += v*w0.x; a0[q*4+1] += v*w0.y; a0[q*4+2] += v*w0.z; a0[q*4+3] += v*w0.w;
            a1[q*4+0] += v*w1.x; a1[q*4+1] += v*w1.y; a1[q*4+2] += v*w1.z; a1[q*4+3] += v*w1.w;
        }
    };
#pragma unroll
    for (int i = 0; i < 32; i++) accum(h[i], i);
#pragma unroll
    for (int i = 0; i < 10; i++) accum(nu[i], 32+i);
#pragma unroll
    for (int i = 0; i < 10; i++) accum(tv[i], 42+i);
#pragma unroll
    for (int i = 0; i < 10; i++) accum(dv[i], 52+i);

    float x0v[32], x1v[32], rv[32];
    float s0 = b_mlp[0], s1 = b_mlp[1], s2 = b_mlp[2], s3 = b_mlp[3];
#pragma unroll
    for (int j = 0; j < 32; j++) {
        float sg0 = 1.f/(1.f + __expf(-a0[j]));
        float sg1 = 1.f/(1.f + __expf(-a1[j]));
        x0v[j] = sg0*h[j]; x1v[j] = sg1*h[j]; rv[j] = h[j] - x0v[j] - x1v[j];
        s0 += h[j]  * W_mlp[j];
        s1 += x0v[j]* W_mlp[32+j];
        s2 += x1v[j]* W_mlp[64+j];
        s3 += rv[j] * W_mlp[96+j];
    }
    float* ho = hist + (size_t)pos*32;
#pragma unroll
    for (int q = 0; q < 8; q++)
        *(float4*)&ho[q*4] = make_float4(h[q*4], h[q*4+1], h[q*4+2], h[q*4+3]);

    unsigned short* fr = fhB + (size_t)pos*288;
#pragma unroll
    for (int q = 0; q < 4; q++) {
        short8v v;
#pragma unroll
        for (int e = 0; e < 8; e++) v[e] = (short)f2bf(fmaxf(h[q*8+e], 0.f));
        *(short8v*)&fr[128 + q*8] = v;
    }
#pragma unroll
    for (int q = 0; q < 4; q++) {
        short8v v;
#pragma unroll
        for (int e = 0; e < 8; e++) v[e] = (short)f2bf(fmaxf(x0v[q*8+e], 0.f));
        *(short8v*)&fr[160 + q*8] = v;
    }
#pragma unroll
    for (int q = 0; q < 4; q++) {
        short8v v;
#pragma unroll
        for (int e = 0; e < 8; e++) v[e] = (short)f2bf(fmaxf(x1v[q*8+e], 0.f));
        *(short8v*)&fr[192 + q*8] = v;
    }
#pragma unroll
    for (int q = 0; q < 4; q++) {
        short8v v;
#pragma unroll
        for (int e = 0; e < 8; e++) v[e] = (short)f2bf(fmaxf(rv[q*8+e], 0.f));
        *(short8v*)&fr[224 + q*8] = v;
    }
    float tail[32];
#pragma unroll
    for (int i = 0; i < 32; i++) tail[i] = (i < 10) ? tv[i] : ((i < 20) ? dv[i-10] : 0.f);
#pragma unroll
    for (int q = 0; q < 4; q++) {
        short8v v;
#pragma unroll
        for (int e = 0; e < 8; e++) v[e] = (short)f2bf(fmaxf(tail[q*8+e], 0.f));
        *(short8v*)&fr[256 + q*8] = v;
    }
    *(float4*)&s4[(size_t)pos*4] = make_float4(s0, s1, s2, s3);
}

// ---------------- K2: ratios ----------------
__global__ void k2_ratio(const float* __restrict__ s4, float* __restrict__ ratio)
{
    int bn = blockIdx.x*256 + threadIdx.x;
    if (bn >= BB*NN) return;
    int b = bn >> 10, n = bn & 1023;
    float a0=0, a1=0, a2=0, a3=0;
    for (int l = 0; l < 12; l++) {
        const float* sp = s4 + ((size_t)(b*12+l)*NN + n)*4;
        a0 += sp[0]; a1 += sp[1]; a2 += sp[2]; a3 += sp[3];
    }
    float hm = a0/12.f;
    float* rp = ratio + (size_t)bn*3;
    rp[0] = (a1/12.f)/(hm + 1e-6f);
    rp[1] = (a2/12.f)/(hm + 1e-6f);
    rp[2] = (a3/12.f)/(hm + 1e-6f);
}

// ---------------- K3: per-b centers ----------------
__global__ __launch_bounds__(256) void k3_centers(const float* __restrict__ ratio, float* __restrict__ centers)
{
    int b = blockIdx.x;
    float m0=-3.4e38f, m1v=-3.4e38f, m2v=-3.4e38f;
    for (int n = threadIdx.x; n < NN; n += 256) {
        const float* rp = ratio + ((size_t)b*NN + n)*3;
        m0 = fmaxf(m0, rp[0]); m1v = fmaxf(m1v, rp[1]); m2v = fmaxf(m2v, rp[2]);
    }
#pragma unroll
    for (int off = 32; off > 0; off >>= 1) {
        m0  = fmaxf(m0,  __shfl_down(m0,  off));
        m1v = fmaxf(m1v, __shfl_down(m1v, off));
        m2v = fmaxf(m2v, __shfl_down(m2v, off));
    }
    __shared__ float red[4][3];
    int wid = threadIdx.x >> 6, lane = threadIdx.x & 63;
    if (lane == 0) { red[wid][0]=m0; red[wid][1]=m1v; red[wid][2]=m2v; }
    __syncthreads();
    if (threadIdx.x == 0) {
        centers[b*3+0] = fmaxf(fmaxf(red[0][0],red[1][0]), fmaxf(red[2][0],red[3][0]));
        centers[b*3+1] = fmaxf(fmaxf(red[0][1],red[1][1]), fmaxf(red[2][1],red[3][1]));
        centers[b*3+2] = fmaxf(fmaxf(red[0][2],red[1][2]), fmaxf(red[2][2],red[3][2]));
    }
}

// ---------------- K4: labels + m1/m2 ----------------
__global__ void k4_labels(const float* __restrict__ ratio, const float* __restrict__ centers,
                          const float* __restrict__ node_u, const float* __restrict__ node_d,
                          int* __restrict__ label, float* __restrict__ m1, float* __restrict__ m2)
{
    int n = blockIdx.x*256 + threadIdx.x;
    if (n >= NN) return;
    int c0=0, c1=0, c2=0;
    for (int b = 0; b < BB; b++) {
        const float* rp = ratio + ((size_t)b*NN + n)*3;
        const float* cp = centers + b*3;
        float d0 = fabsf(rp[0]-cp[0]), d1 = fabsf(rp[1]-cp[1]), d2 = fabsf(rp[2]-cp[2]);
        int a = 0; float best = d0;
        if (d1 < best) { best = d1; a = 1; }
        if (d2 < best) { best = d2; a = 2; }
        if (a == 0) c0++; else if (a == 1) c1++; else c2++;
    }
    int lab = 0, bc = c0;
    if (c1 > bc) { bc = c1; lab = 1; }
    if (c2 > bc) { bc = c2; lab = 2; }
    label[n] = lab;
#pragma unroll
    for (int d = 0; d < 10; d++) {
        m1[n*10+d] = tanhf(kALPHA*node_u[n*10+d]);
        m2[n*10+d] = tanhf(kALPHA*node_d[n*10+d]);
    }
}

// ---------------- K5: An ----------------
__global__ __launch_bounds__(256) void k5_A(const float* __restrict__ m1, const float* __restrict__ m2,
                                            const int* __restrict__ label, float* __restrict__ An)
{
    int n = blockIdx.x;
    __shared__ float row[1024];
    __shared__ float m1n[10], m2n[10];
    __shared__ float ssum[4];
    int t = threadIdx.x;
    if (t < 10) { m1n[t] = m1[n*10+t]; m2n[t] = m2[n*10+t]; }
    __syncthreads();
    int labn = label[n];
    float lsum = 0.f;
    for (int m = t; m < 1024; m += 256) {
        float a = 0.f;
        if (label[m] == labn) {
            float x = 0.f;
#pragma unroll
            for (int d = 0; d < 10; d++) x += m1n[d]*m2[m*10+d] - m2n[d]*m1[m*10+d];
            a = fmaxf(tanhf(3.f*x), 0.f);
        }
        row[m] = a; lsum += a;
    }
#pragma unroll
    for (int off = 32; off > 0; off >>= 1) lsum += __shfl_down(lsum, off);
    int wid = t >> 6, lane = t & 63;
    if (lane == 0) ssum[wid] = lsum;
    __syncthreads();
    float inv = 1.f/((ssum[0]+ssum[1]+ssum[2]+ssum[3]) + 1e-6f);
    for (int m = t; m < 1024; m += 256) An[(size_t)n*1024 + m] = row[m]*inv;
}

// ---------------- transpose fp32 [R][C] -> bf16 outT[C][R] ----------------
template<bool ALSO_DIRECT>
__global__ __launch_bounds__(256) void kt_transpose(const float* __restrict__ in,
                                                    unsigned short* __restrict__ outT,
                                                    unsigned short* __restrict__ outD,
                                                    int R, int C)
{
    __shared__ float tile[64][65];
    int c0 = blockIdx.x*64, r0 = blockIdx.y*64;
    for (int i = threadIdx.x; i < 64*64; i += 256) {
        int r = i >> 6, c = i & 63;
        float v = in[(size_t)(r0+r)*C + c0+c];
        tile[r][c] = v;
        if (ALSO_DIRECT) outD[(size_t)(r0+r)*C + c0+c] = f2bf(v);
    }
    __syncthreads();
    for (int i = threadIdx.x; i < 64*64; i += 256) {
        int c = i >> 6, r = i & 63;
        outT[(size_t)(c0+c)*R + r0+r] = f2bf(tile[r][c]);
    }
}

// ---------------- bf16 MFMA GEMM, 128x128 tile, BK=64, 2-phase dbuf ----------------
// MODE 0: AcombB(bf16) = bf16(0.9025*acc + 0.0475*A + 0.05*I)
// MODE 2: C(bf16) = acc
template<int MODE>
__global__ __launch_bounds__(256) void gemm_mfma(
    const unsigned short* __restrict__ A, const unsigned short* __restrict__ B,
    void* __restrict__ Cout, int Nout, int K)
{
    __shared__ __align__(16) unsigned short lds[2][2][2][128*32];   // 64 KB
    const int t = threadIdx.x;

    int id = blockIdx.x + gridDim.x*blockIdx.y;
    int gx8 = gridDim.x >> 3;
    int xcd = id & 7, local = id >> 3;
    int bx = xcd*gx8 + (local % gx8);
    int by = local / gx8;

    const int lane = t & 63, wid = t >> 6;
    const int wr = wid >> 1, wc = wid & 1;
    const int l15 = lane & 15, l4 = lane >> 4;
    const int swq8 = (l4 ^ ((l15 >> 1) & 3))*8;
    const int row0 = by*128, col0 = bx*128;

    float4v acc[4][4];
#pragma unroll
    for (int i = 0; i < 4; i++)
#pragma unroll
        for (int j = 0; j < 4; j++) acc[i][j] = (float4v){0.f,0.f,0.f,0.f};

    const unsigned short* Ab = A + (size_t)row0*K;
    const unsigned short* Bb = B + (size_t)col0*K;

    stage_tile(Ab +  0, K, lds[0][0][0], t); stage_tile(Bb +  0, K, lds[0][1][0], t);
    stage_tile(Ab + 32, K, lds[0][0][1], t); stage_tile(Bb + 32, K, lds[0][1][1], t);
    __syncthreads();

    const int nk = K >> 6;
    for (int ks = 0; ks < nk; ks++) {
        int cur = ks & 1;
        if (ks + 1 < nk) {
            stage_tile(Ab + (ks+1)*64,      K, lds[cur^1][0][0], t);
            stage_tile(Bb + (ks+1)*64,      K, lds[cur^1][1][0], t);
            stage_tile(Ab + (ks+1)*64 + 32, K, lds[cur^1][0][1], t);
            stage_tile(Bb + (ks+1)*64 + 32, K, lds[cur^1][1][1], t);
        }
#pragma unroll
        for (int kk = 0; kk < 2; kk++) {
            short8v a[4], b[4];
#pragma unroll
            for (int f = 0; f < 4; f++) {
                a[f] = *(const short8v*)&lds[cur][0][kk][(wr*64 + f*16 + l15)*32 + swq8];
                b[f] = *(const short8v*)&lds[cur][1][kk][(wc*64 + f*16 + l15)*32 + swq8];
            }
#pragma unroll
            for (int i = 0; i < 4; i++)
#pragma unroll
                for (int j = 0; j < 4; j++)
                    acc[i][j] = __builtin_amdgcn_mfma_f32_16x16x32_bf16(a[i], b[j], acc[i][j], 0, 0, 0);
        }
        __syncthreads();
    }

#pragma unroll
    for (int i = 0; i < 4; i++) {
#pragma unroll
        for (int j = 0; j < 4; j++) {
            int gc = col0 + wc*64 + j*16 + l15;
#pragma unroll
            for (int r = 0; r < 4; r++) {
                int gr = row0 + wr*64 + i*16 + l4*4 + r;
                if (MODE == 0) {
                    float an = bf2f(A[(size_t)gr*K + gc]);
                    float v = 0.9025f*acc[i][j][r] + 0.0475f*an + ((gr==gc) ? 0.05f : 0.f);
                    ((unsigned short*)Cout)[(size_t)gr*Nout + gc] = f2bf(v);
                } else {
                    ((unsigned short*)Cout)[(size_t)gr*Nout + gc] = f2bf(acc[i][j][r]);
                }
            }
        }
    }
}

// ---------------- K7T: fused x0 compute + transpose -> x0T bf16 [8192 col][1024 n] ----------------
__global__ __launch_bounds__(256) void k7t_x0T(
    const float* __restrict__ hist, const float* __restrict__ W_start, const float* __restrict__ b_start,
    unsigned short* __restrict__ x0T)
{
    __shared__ float hl[12*1056];   // [l][nn*33 + h]
    __shared__ float sw[384];       // [c*12+l]
    __shared__ float sb[32];

    const int b = blockIdx.x >> 5;
    const int n0 = (blockIdx.x & 31)*32;
    const int t = threadIdx.x;

    for (int i = t; i < 384; i += 256) sw[i] = W_start[i];
    if (t < 32) sb[t] = b_start[t];
#pragma unroll
    for (int l = 0; l < 12; l++) {
        float4 v = ((const float4*)(hist + ((size_t)(b*12+l)*NN + n0)*32))[t];
        int nn = t >> 3, h4 = (t & 7)*4;
        float* d = &hl[l*1056 + nn*33 + h4];
        d[0] = v.x; d[1] = v.y; d[2] = v.z; d[3] = v.w;
    }
    __syncthreads();

    const int n = t & 31;
    const int c0base = t >> 5;
    for (int it = 0; it < 128; it++) {
        int col = c0base + it*8;
        int c = col >> 5, h = col & 31;
        float s = sb[c];
#pragma unroll
        for (int l = 0; l < 12; l++) s += sw[c*12+l]*hl[l*1056 + n*33 + h];
        x0T[((size_t)(b*1024 + col))*1024 + n0 + n] = f2bf(s);
    }
}

// ---------------- Kw: wcomboT bf16 [128 j][32 h] + we1B bf16 [128 o1][32 c] ----------------
__global__ void kw_combo2(const float* __restrict__ W_g, const float* __restrict__ W_rnn,
                          const float* __restrict__ W_e1,
                          unsigned short* __restrict__ wcomboT, unsigned short* __restrict__ we1B)
{
    int j = threadIdx.x;  // 128
    for (int hh = 0; hh < 32; hh++) {
        float s = 0.f;
        for (int k = 0; k < 32; k++) s += (W_g[hh*32+k] + W_g[1024 + hh*32+k]) * W_rnn[k*128 + j];
        wcomboT[j*32 + hh] = f2bf(s);
    }
    for (int i = j; i < 4096; i += 128) we1B[i] = f2bf(W_e1[i]);
}

// ---------------- K9 MFMA ----------------
__global__ __launch_bounds__(256) void k9_mfma(
    const unsigned short* __restrict__ hfinB,    // [N][8192] bf16
    const unsigned short* __restrict__ wcomboT,  // [128][32] bf16
    const float* __restrict__ b_rnn,
    const unsigned short* __restrict__ we1B,     // [128][32] bf16
    const float* __restrict__ b_e1,
    const float* __restrict__ W_e2,              // [12][128]
    const float* __restrict__ b_e2,
    const float* __restrict__ Mm,                // [N][128]
    unsigned short* __restrict__ fhB)            // [98304][288], cols 0..127
{
    __shared__ __align__(16) unsigned short xrT[4][1024];
    __shared__ float sWe2T[128][12];
    __shared__ float sBe1[128];
    __shared__ float sBe2[16];

    const int t = threadIdx.x;
    const int bid = blockIdx.x;
    const int n = bid & (NN-1), b = bid >> 10;
    const int lane = t & 63, wid = t >> 6;
    const int l15 = lane & 15, l4 = lane >> 4;
    const int j0 = wid*32;

    for (int i = t; i < 12*128; i += 256) {
        int o2 = i >> 7, o1 = i & 127;
        sWe2T[o1][o2] = W_e2[i];
    }
    if (t < 128) sBe1[t] = b_e1[t];
    if (t < 12)  sBe2[t] = b_e2[t];
    __syncthreads();

    const unsigned short* Hb = hfinB + (size_t)n*8192 + (size_t)b*1024;
    short8v ah[2], bw[2];
#pragma unroll
    for (int f = 0; f < 2; f++) {
        ah[f] = *(const short8v*)&Hb[(f*16 + l15)*32 + l4*8];
        bw[f] = *(const short8v*)&wcomboT[(j0 + f*16 + l15)*32 + l4*8];
    }
    float br[2];
    br[0] = b_rnn[j0 + l15];
    br[1] = b_rnn[j0 + 16 + l15];
    float4v accA[2][2];
#pragma unroll
    for (int cf = 0; cf < 2; cf++)
#pragma unroll
        for (int jf = 0; jf < 2; jf++)
            accA[cf][jf] = (float4v){br[jf], br[jf], br[jf], br[jf]};
#pragma unroll
    for (int cf = 0; cf < 2; cf++)
#pragma unroll
        for (int jf = 0; jf < 2; jf++)
            accA[cf][jf] = __builtin_amdgcn_mfma_f32_16x16x32_bf16(ah[cf], bw[jf], accA[cf][jf], 0, 0, 0);

#pragma unroll
    for (int cf = 0; cf < 2; cf++)
#pragma unroll
        for (int jf = 0; jf < 2; jf++) {
            int jl = jf*16 + l15;
            int csw = (cf*16 + l4*4) ^ ((jl & 3) << 3);
            unsigned short p0 = f2bf(tanhf(accA[cf][jf][0]));
            unsigned short p1 = f2bf(tanhf(accA[cf][jf][1]));
            unsigned short p2 = f2bf(tanhf(accA[cf][jf][2]));
            unsigned short p3 = f2bf(tanhf(accA[cf][jf][3]));
            unsigned int lo = (unsigned)p0 | ((unsigned)p1 << 16);
            unsigned int hi = (unsigned)p2 | ((unsigned)p3 << 16);
            *(uint2*)&xrT[wid][jl*32 + csw] = make_uint2(lo, hi);
        }

    short8v bx[2];
#pragma unroll
    for (int jf = 0; jf < 2; jf++) {
        int jl = jf*16 + l15;
        int csw = (l4*8) ^ ((jl & 3) << 3);
        bx[jf] = *(const short8v*)&xrT[wid][jl*32 + csw];
    }
    float4v accB[8][2];
#pragma unroll
    for (int of = 0; of < 8; of++)
#pragma unroll
        for (int jf = 0; jf < 2; jf++) accB[of][jf] = (float4v){0.f,0.f,0.f,0.f};
#pragma unroll
    for (int of = 0; of < 8; of++) {
        short8v aw = *(const short8v*)&we1B[(of*16 + l15)*32 + l4*8];
        accB[of][0] = __builtin_amdgcn_mfma_f32_16x16x32_bf16(aw, bx[0], accB[of][0], 0, 0, 0);
        accB[of][1] = __builtin_amdgcn_mfma_f32_16x16x32_bf16(aw, bx[1], accB[of][1], 0, 0, 0);
    }

    float v0[12], v1[12];
#pragma unroll
    for (int o2 = 0; o2 < 12; o2++) { v0[o2] = 0.f; v1[o2] = 0.f; }
#pragma unroll
    for (int of = 0; of < 8; of++) {
#pragma unroll
        for (int r = 0; r < 4; r++) {
            int o1 = of*16 + l4*4 + r;
            float be = sBe1[o1];
            float z0 = fmaxf(accB[of][0][r] + be, 0.f);
            float z1 = fmaxf(accB[of][1][r] + be, 0.f);
#pragma unroll
            for (int q = 0; q < 3; q++) {
                float4 w = *(const float4*)&sWe2T[o1][q*4];
                v0[q*4+0] += w.x*z0; v0[q*4+1] += w.y*z0; v0[q*4+2] += w.z*z0; v0[q*4+3] += w.w*z0;
                v1[q*4+0] += w.x*z1; v1[q*4+1] += w.y*z1; v1[q*4+2] += w.z*z1; v1[q*4+3] += w.w*z1;
            }
        }
    }
#pragma unroll
    for (int o2 = 0; o2 < 12; o2++) {
        v0[o2] += __shfl_xor(v0[o2], 16);
        v0[o2] += __shfl_xor(v0[o2], 32);
        v1[o2] += __shfl_xor(v1[o2], 16);
        v1[o2] += __shfl_xor(v1[o2], 32);
    }

    float mm0 = Mm[(size_t)n*128 + j0 + l15];
    float mm1 = Mm[(size_t)n*128 + j0 + 16 + l15];
#pragma unroll
    for (int e = 0; e < 3; e++) {
        int o2 = l4*3 + e;
        float be2 = sBe2[o2];
        size_t base = ((size_t)((b*12 + o2)*NN + n))*288;
        float val0 = (v0[o2] + be2) * mm0;
        float val1 = (v1[o2] + be2) * mm1;
        fhB[base + j0 + l15]      = f2bf(fmaxf(val0, 0.f));
        fhB[base + j0 + 16 + l15] = f2bf(fmaxf(val1, 0.f));
    }
}

// ---------------- kt_w1: W_f1 -> bf16 [512][288] (n-major) ----------------
__global__ void kt_w1(const float* __restrict__ W_f1, unsigned short* __restrict__ w1hi)
{
    int idx = blockIdx.x*256 + threadIdx.x;
    if (idx >= 512*288) return;
    int n = idx / 288, k = idx - n*288;
    float w = (k < 276) ? W_f1[(size_t)k*512 + n] : 0.f;
    w1hi[idx] = f2bf(w);
}

// ---------------- K10 (best measured): one block per 128-row stripe, ALL 512 cols, hi-only ----------------
// __launch_bounds__(512, 2): 256-VGPR budget so acc[4][8] stays in registers.
// LDS 80 KB (fcp aliases Abuf). Direct fc store, no atomics.
__global__ __launch_bounds__(512, 2) void k10_mfma2(
    const unsigned short* __restrict__ fhB, const unsigned short* __restrict__ w1hi,
    const float* __restrict__ b_f1, const float* __restrict__ W_f2, float* __restrict__ fc)
{
    __shared__ __align__(16) unsigned short smem[40960];   // 80 KB
    unsigned short (*Abuf)[128*32]  = (unsigned short(*)[128*32])smem;            // 16 KB
    unsigned short (*Bhbuf)[512*32] = (unsigned short(*)[512*32])(smem + 8192);   // 64 KB
    float* fcp = (float*)smem;                                                     // epilogue alias

    const int t = threadIdx.x;
    int id = blockIdx.x;                         // 768 blocks
    int by = (id & 7)*96 + (id >> 3);            // XCD-chunked, bijective (768 = 8*96)
    const int pos0 = by*128;

    const int lane = t & 63, w = t >> 6;
    const int wr = w >> 2, wc = w & 3;
    const int l15 = lane & 15, l4 = lane >> 4;
    const int swq8 = (l4 ^ ((l15 >> 1) & 3))*8;

    float4v acc[4][8];
#pragma unroll
    for (int i = 0; i < 4; i++)
#pragma unroll
        for (int j = 0; j < 8; j++) acc[i][j] = (float4v){0.f,0.f,0.f,0.f};

    const unsigned short* Ab = fhB + (size_t)pos0*288;

    stage_tileA512(Ab,   288, Abuf[0],  t);
    stage_tileB512(w1hi, 288, Bhbuf[0], t);
    __syncthreads();

    for (int ks = 0; ks < 9; ks++) {
        int cur = ks & 1;
        if (ks + 1 < 9) {
            stage_tileA512(Ab   + (ks+1)*32, 288, Abuf[cur^1],  t);
            stage_tileB512(w1hi + (ks+1)*32, 288, Bhbuf[cur^1], t);
        }
        short8v a[4];
#pragma unroll
        for (int f = 0; f < 4; f++)
            a[f] = *(const short8v*)&Abuf[cur][(wr*64 + f*16 + l15)*32 + swq8];
#pragma unroll
        for (int j = 0; j < 8; j++) {
            int brow = wc*128 + j*16 + l15;
            short8v bh = *(const short8v*)&Bhbuf[cur][brow*32 + swq8];
#pragma unroll
            for (int i = 0; i < 4; i++)
                acc[i][j] = __builtin_amdgcn_mfma_f32_16x16x32_bf16(a[i], bh, acc[i][j], 0, 0, 0);
        }
        __syncthreads();
    }

    // epilogue: fcp (aliases Abuf) zero, then z = relu(acc+b), contract with W_f2
    for (int i = t; i < 384; i += 512) fcp[i] = 0.f;
    __syncthreads();

    float pk[4][4][3];
#pragma unroll
    for (int i = 0; i < 4; i++)
#pragma unroll
        for (int r = 0; r < 4; r++)
#pragma unroll
            for (int k = 0; k < 3; k++) pk[i][r][k] = 0.f;

#pragma unroll
    for (int j = 0; j < 8; j++) {
        int gc = wc*128 + j*16 + l15;
        float bias = b_f1[gc];
        float w20 = W_f2[gc*3+0], w21 = W_f2[gc*3+1], w22 = W_f2[gc*3+2];
#pragma unroll
        for (int i = 0; i < 4; i++)
#pragma unroll
            for (int r = 0; r < 4; r++) {
                float z = fmaxf(acc[i][j][r] + bias, 0.f);
                pk[i][r][0] += z*w20; pk[i][r][1] += z*w21; pk[i][r][2] += z*w22;
            }
    }
#pragma unroll
    for (int i = 0; i < 4; i++)
#pragma unroll
        for (int r = 0; r < 4; r++) {
            int rowL = wr*64 + i*16 + l4*4 + r;
            atomicAdd(&fcp[rowL*3 + 0], pk[i][r][0]);
            atomicAdd(&fcp[rowL*3 + 1], pk[i][r][1]);
            atomicAdd(&fcp[rowL*3 + 2], pk[i][r][2]);
        }
    __syncthreads();
    for (int i = t; i < 384; i += 512) {
        fc[(size_t)pos0*3 + i] = fcp[i];
    }
}

// ---------------- K11: e3 epilogue + transpose ----------------
__global__ void k11_e3(const float* __restrict__ fc, const float* __restrict__ b_f2,
                       const float* __restrict__ W_e3, const float* __restrict__ b_e3,
                       float* __restrict__ out)
{
    int idx = blockIdx.x*256 + threadIdx.x;
    if (idx >= BB*NN*12) return;
    int ok = idx % 12;
    int o = ok / 3, k = ok % 3;
    int bn = idx / 12;
    int n = bn & 1023, b = bn >> 10;
    float s = b_e3[o];
    float bk = b_f2[k];
#pragma unroll
    for (int c = 0; c < 12; c++)
        s += W_e3[o*12+c] * (fc[((size_t)(b*12+c)*NN + n)*3 + k] + bk);
    out[idx] = s;
}

extern "C" void kernel_launch(void* const* d_in, const int* in_sizes, int n_in,
                              void* d_out, int out_size, void* d_ws, size_t ws_size,
                              hipStream_t stream)
{
    const float* hd      = (const float*)d_in[0];
    const float* W_emb   = (const float*)d_in[1];
    const float* b_emb   = (const float*)d_in[2];
    const float* T_emb   = (const float*)d_in[3];
    const float* D_emb   = (const float*)d_in[4];
    const float* node_u  = (const float*)d_in[5];
    const float* node_d  = (const float*)d_in[6];
    const float* W_std   = (const float*)d_in[7];
    const float* b_std   = (const float*)d_in[8];
    const float* W_mlp   = (const float*)d_in[9];
    const float* b_mlp   = (const float*)d_in[10];
    const float* W_start = (const float*)d_in[11];
    const float* b_start = (const float*)d_in[12];
    const float* W_g     = (const float*)d_in[13];
    const float* W_rnn   = (const float*)d_in[14];
    const float* b_rnn   = (const float*)d_in[15];
    const float* W_e1    = (const float*)d_in[16];
    const float* b_e1    = (const float*)d_in[17];
    const float* W_e2    = (const float*)d_in[18];
    const float* b_e2    = (const float*)d_in[19];
    const float* Mm      = (const float*)d_in[20];
    const float* W_f1    = (const float*)d_in[21];
    const float* b_f1    = (const float*)d_in[22];
    const float* W_f2    = (const float*)d_in[23];
    const float* b_f2    = (const float*)d_in[24];
    const float* W_e3    = (const float*)d_in[25];
    const float* b_e3    = (const float*)d_in[26];

    float* ws      = (float*)d_ws;
    float* hist    = ws + OFF_HIST;
    float* s4      = ws + OFF_S4;
    float* ratio   = ws + OFF_RATIO;
    float* cent    = ws + OFF_CENT;
    float* m1      = ws + OFF_M1;
    float* m2      = ws + OFF_M2;
    int*   label   = (int*)(ws + OFF_LABEL);
    float* An      = ws + OFF_AN;
    unsigned short* AcombB  = (unsigned short*)(ws + OFF_ACOMBB);
    unsigned short* hfinB   = (unsigned short*)(ws + OFF_HFINB);
    unsigned short* wcomboT = (unsigned short*)(ws + OFF_WCOMBOT);
    unsigned short* we1B    = (unsigned short*)(ws + OFF_WE1B);
    float* fc      = ws + OFF_FC;
    unsigned short* AnB   = (unsigned short*)(ws + OFF_ANB);
    unsigned short* AnBT  = (unsigned short*)(ws + OFF_ANBT);
    unsigned short* x0T   = (unsigned short*)(ws + OFF_X0T);
    unsigned short* w1hi  = (unsigned short*)(ws + OFF_W1HI);
    unsigned short* fhB   = (unsigned short*)(ws + OFF_FHB);

    k1_embed<<<(BB*LL*NN)/256, 256, 0, stream>>>(hd, W_emb, b_emb, T_emb, D_emb, node_u,
                                                 W_std, b_std, W_mlp, b_mlp, hist, fhB, s4);
    k2_ratio<<<(BB*NN)/256, 256, 0, stream>>>(s4, ratio);
    k3_centers<<<BB, 256, 0, stream>>>(ratio, cent);
    k4_labels<<<NN/256, 256, 0, stream>>>(ratio, cent, node_u, node_d, label, m1, m2);
    k5_A<<<NN, 256, 0, stream>>>(m1, m2, label, An);
    kt_transpose<true><<<dim3(16, 16), 256, 0, stream>>>(An, AnBT, AnB, 1024, 1024);
    gemm_mfma<0><<<dim3(8, 8), 256, 0, stream>>>(AnB, AnBT, AcombB, 1024, 1024);
    k7t_x0T<<<256, 256, 0, stream>>>(hist, W_start, b_start, x0T);
    gemm_mfma<2><<<dim3(64, 8), 256, 0, stream>>>(AcombB, x0T, hfinB, 8192, 1024);
    kw_combo2<<<1, 128, 0, stream>>>(W_g, W_rnn, W_e1, wcomboT, we1B);
    k9_mfma<<<BB*NN, 256, 0, stream>>>(hfinB, wcomboT, b_rnn, we1B, b_e1, W_e2, b_e2, Mm, fhB);
    kt_w1<<<(512*288)/256, 256, 0, stream>>>(W_f1, w1hi);
    k10_mfma2<<<768, 512, 0, stream>>>(fhB, w1hi, b_f1, W_f2, fc);
    k11_e3<<<(BB*NN*12)/256, 256, 0, stream>>>(fc, b_f2, W_e3, b_e3, (float*)d_out);
}